// Round 5
// baseline (159.919 us; speedup 1.0000x reference)
//
#include <hip/hip_runtime.h>

// CRS rate-and-state model. R -> et*R/(1+c*R) is a Mobius map [[a,0],[c,1]];
// these compose associatively, so the whole T=4096 row is ONE two-level scan:
// one 256-thread block per row, lane owns 16 contiguous steps.
//   phase 1: per-lane compose (A,C) over 16 steps  (exps independent)
//   phase 2: 6-round wave shuffle-scan + 4 wave-totals via LDS (barrier)
//   phase 3: closed-form outputs R_j = A_j*R~/(1+C_j*R~);
//            den_j telescopes: den_j = L_j/L_{j-1}, L_j = 1+C_j*R~
//   phase 4: wave+block prefix-sum of per-lane N totals (barrier), store.
// R5 rationale: R1-R4 (one wave/row, 8-16 sequential tiles) were pinned at
// 148-160us by per-tile serial scan chains + unhideable load latency
// (compiler kept sinking the prefetch; VGPR stayed 32-60). This removes the
// tile loop: 13 scan rounds per row instead of 96, no carry chain, no
// prefetch needed.

#define C_TNSR  0.001f
#define C_TSSR  0.002f
#define C_SIGMA 50.0f
#define C_BIOT  0.3f
#define C_R0    0.0001f
#define C_N0    0.0001f

constexpr int B = 8192;
constexpr int T = 4096;
constexpr int STEPS = 16;          // per lane
constexpr int WAVES = 4;           // 256 threads per block = one row

typedef float f4 __attribute__((ext_vector_type(4)));

__global__ __launch_bounds__(256, 4)
void crs_row_kernel(const float* __restrict__ params,
                    const float* __restrict__ p,
                    const float* __restrict__ dpdt,
                    const float* __restrict__ dtv,
                    float* __restrict__ Rt,
                    float* __restrict__ Nt)
{
    __shared__ float sA[WAVES], sC[WAVES], sS[WAVES];

    const int tid  = threadIdx.x;
    const int lane = tid & 63;
    const int wid  = tid >> 6;
    const int b    = blockIdx.x;

    const float mu  = params[b * 3 + 0];
    const float rc  = params[b * 3 + 1];
    const float rf  = params[b * 3 + 2];
    const float eta = 1.0f / rf;
    const float rcS = rc * C_SIGMA;
    const float rcB = rc * C_BIOT;

    const int seg = tid * STEPS;   // this lane's first step in the row
    const float* __restrict__ prow = p    + (size_t)b * T + seg;
    const float* __restrict__ drow = dpdt + (size_t)b * T + seg;
    const float* __restrict__ trow = dtv  + (size_t)b * T + seg;
    float* __restrict__ Rrow = Rt + (size_t)b * (T + 1) + 1;
    float* __restrict__ Nrow = Nt + (size_t)b * (T + 1) + 1;

    if (tid == 0) { Rrow[-1] = C_R0; Nrow[-1] = C_N0; }

    // ---- load this lane's 16 steps (3 streams x 4 f4, issued upfront) ----
    f4 pv[4], dv[4], tv[4];
#pragma unroll
    for (int q = 0; q < 4; ++q) pv[q] = *(const f4*)(prow + 4 * q);
#pragma unroll
    for (int q = 0; q < 4; ++q) dv[q] = *(const f4*)(drow + 4 * q);
#pragma unroll
    for (int q = 0; q < 4; ++q) tv[q] = *(const f4*)(trow + 4 * q);

    // ---- phase 1: per-lane inclusive Mobius prefixes ----
    float Aj[STEPS], Cj[STEPS], kk[STEPS];
    float A = 1.0f, C = 0.0f;
#pragma unroll
    for (int j = 0; j < STEPS; ++j) {
        float pp = pv[j >> 2][j & 3];
        float dd = dv[j >> 2][j & 3];
        float tt = tv[j >> 2][j & 3];
        float sd   = C_TSSR - mu * (C_TNSR - dd);
        float asig = fmaf(-rcB, pp, rcS);
        float e    = __expf(__fdividef(sd * tt, asig));
        float c    = __fdividef(eta * (e - 1.0f), sd);
        kk[j] = asig * rf;               // asig/eta
        C = fmaf(c, A, C);               // compose step j after (A,C)
        A = A * e;
        Aj[j] = A;
        Cj[j] = C;
    }

    // ---- phase 2a: wave-inclusive scan of (A,C) ----
#pragma unroll
    for (int o = 1; o < 64; o <<= 1) {
        float Ap = __shfl_up(A, (unsigned)o, 64);
        float Cp = __shfl_up(C, (unsigned)o, 64);
        if (lane >= o) { C = fmaf(C, Ap, Cp); A = A * Ap; }
    }
    float Ae = __shfl_up(A, 1u, 64);
    float Ce = __shfl_up(C, 1u, 64);
    if (lane == 0) { Ae = 1.0f; Ce = 0.0f; }

    // ---- phase 2b: cross-wave composition via LDS ----
    if (lane == 63) { sA[wid] = A; sC[wid] = C; }
    __syncthreads();
    float PA = 1.0f, PC = 0.0f;          // composition of waves < wid
#pragma unroll
    for (int w = 0; w < WAVES - 1; ++w) {
        if (w < wid) { PC = fmaf(sC[w], PA, PC); PA = sA[w] * PA; }
    }
    // exclusive map for this lane = laneExcl ∘ priorWaves
    float EA = Ae * PA;
    float EC = fmaf(Ce, PA, PC);
    // R entering this lane's 16-step segment
    float Rt_ = __fdividef(EA * C_R0, fmaf(EC, C_R0, 1.0f));

    // ---- phase 3: closed-form outputs (all divides/logs independent) ----
    // L_j = 1 + Cj*R~ ; R_j = Aj*R~ / L_j ; den_j = L_j / L_{j-1}, L_{-1}=1
    float rl[STEPS], Lj[STEPS];
#pragma unroll
    for (int j = 0; j < STEPS; ++j) {
        Lj[j] = fmaf(Cj[j], Rt_, 1.0f);
        rl[j] = __fdividef(1.0f, Lj[j]);
        Rrow[seg + j] = (Aj[j] * Rt_) * rl[j];
    }
    float nn[STEPS];
    float ns = 0.0f;
#pragma unroll
    for (int j = 0; j < STEPS; ++j) {
        float den = (j == 0) ? Lj[0] : Lj[j] * rl[j - 1];
        ns += kk[j] * __logf(den);
        nn[j] = ns;
    }

    // ---- phase 4: two-level prefix sum of per-lane N totals ----
    float S = ns;
#pragma unroll
    for (int o = 1; o < 64; o <<= 1) {
        float Sp = __shfl_up(S, (unsigned)o, 64);
        if (lane >= o) S += Sp;
    }
    if (lane == 63) sS[wid] = S;
    __syncthreads();
    float PS = C_N0;
#pragma unroll
    for (int w = 0; w < WAVES - 1; ++w) {
        if (w < wid) PS += sS[w];
    }
    float base = PS + (S - ns);          // global exclusive prefix + N0

#pragma unroll
    for (int j = 0; j < STEPS; ++j)
        Nrow[seg + j] = base + nn[j];
}

extern "C" void kernel_launch(void* const* d_in, const int* in_sizes, int n_in,
                              void* d_out, int out_size, void* d_ws, size_t ws_size,
                              hipStream_t stream)
{
    const float* params = (const float*)d_in[0];
    const float* p      = (const float*)d_in[1];
    const float* dpdt   = (const float*)d_in[2];
    const float* dtv    = (const float*)d_in[3];

    float* Rt = (float*)d_out;                       // B*(T+1)
    float* Nt = (float*)d_out + (size_t)B * (T + 1); // B*(T+1)

    crs_row_kernel<<<B, 256, 0, stream>>>(params, p, dpdt, dtv, Rt, Nt);
}

// Round 6
// 138.769 us; speedup vs baseline: 1.1524x; 1.1524x over previous
//
#include <hip/hip_runtime.h>

// CRS rate-and-state model. R -> et*R/(1+c*R) is a Mobius map [[a,0],[c,1]];
// maps compose associatively -> whole T=4096 row is ONE two-level scan:
// one 256-thread block per row, lane owns 16 contiguous steps.
// R6: aligned store stage. Output rows start at dword b*4097+1, so every 64B
// output line was split across store instructions -> L2 write-allocate did a
// read-modify-write fetch of the whole 268MB output footprint (the invariant
// drag across R1-R5). Now: results bounce through skew-indexed LDS
// (idx = m + (m>>5), <=2-way banks = free), then per-row phase shift s makes
// the bulk dwordx4 stores 64B-aligned -> 16 FULL lines per wave-store, no RMW.

#define C_TNSR  0.001f
#define C_TSSR  0.002f
#define C_SIGMA 50.0f
#define C_BIOT  0.3f
#define C_R0    0.0001f
#define C_N0    0.0001f

constexpr int B = 8192;
constexpr int T = 4096;
constexpr int STEPS = 16;          // per lane
constexpr int WAVES = 4;           // 256 threads per block = one row

typedef float f4 __attribute__((ext_vector_type(4)));

__device__ __forceinline__ int SIDX(int m) { return m + (m >> 5); }

__global__ __launch_bounds__(256, 4)
void crs_row_kernel(const float* __restrict__ params,
                    const float* __restrict__ p,
                    const float* __restrict__ dpdt,
                    const float* __restrict__ dtv,
                    float* __restrict__ Rt,
                    float* __restrict__ Nt)
{
    __shared__ float lsR[T + T / 32];   // 16.5 KB, skew-indexed
    __shared__ float lsN[T + T / 32];
    __shared__ float sA[WAVES], sC[WAVES], sS[WAVES];

    const int tid  = threadIdx.x;
    const int lane = tid & 63;
    const int wid  = tid >> 6;
    const int b    = blockIdx.x;

    const float mu  = params[b * 3 + 0];
    const float rc  = params[b * 3 + 1];
    const float rf  = params[b * 3 + 2];
    const float eta = 1.0f / rf;
    const float rcS = rc * C_SIGMA;
    const float rcB = rc * C_BIOT;

    const int seg = tid * STEPS;
    const float* __restrict__ prow = p    + (size_t)b * T + seg;
    const float* __restrict__ drow = dpdt + (size_t)b * T + seg;
    const float* __restrict__ trow = dtv  + (size_t)b * T + seg;

    // ---- load this lane's 16 steps (64B-aligned dwordx4, dense) ----
    f4 pv[4], dv[4], tv[4];
#pragma unroll
    for (int q = 0; q < 4; ++q) pv[q] = *(const f4*)(prow + 4 * q);
#pragma unroll
    for (int q = 0; q < 4; ++q) dv[q] = *(const f4*)(drow + 4 * q);
#pragma unroll
    for (int q = 0; q < 4; ++q) tv[q] = *(const f4*)(trow + 4 * q);

    // ---- phase 1: per-lane inclusive Mobius prefixes ----
    float Aj[STEPS], Cj[STEPS], kk[STEPS];
    float A = 1.0f, C = 0.0f;
#pragma unroll
    for (int j = 0; j < STEPS; ++j) {
        float pp = pv[j >> 2][j & 3];
        float dd = dv[j >> 2][j & 3];
        float tt = tv[j >> 2][j & 3];
        float sd   = C_TSSR - mu * (C_TNSR - dd);
        float asig = fmaf(-rcB, pp, rcS);
        float e    = __expf(__fdividef(sd * tt, asig));
        float c    = __fdividef(eta * (e - 1.0f), sd);
        kk[j] = asig * rf;               // asig/eta
        C = fmaf(c, A, C);               // compose step j after (A,C)
        A = A * e;
        Aj[j] = A;
        Cj[j] = C;
    }

    // ---- phase 2a: wave-inclusive scan of (A,C) ----
#pragma unroll
    for (int o = 1; o < 64; o <<= 1) {
        float Ap = __shfl_up(A, (unsigned)o, 64);
        float Cp = __shfl_up(C, (unsigned)o, 64);
        if (lane >= o) { C = fmaf(C, Ap, Cp); A = A * Ap; }
    }
    float Ae = __shfl_up(A, 1u, 64);
    float Ce = __shfl_up(C, 1u, 64);
    if (lane == 0) { Ae = 1.0f; Ce = 0.0f; }

    // ---- phase 2b: cross-wave composition via LDS ----
    if (lane == 63) { sA[wid] = A; sC[wid] = C; }
    __syncthreads();
    float PA = 1.0f, PC = 0.0f;
#pragma unroll
    for (int w = 0; w < WAVES - 1; ++w) {
        if (w < wid) { PC = fmaf(sC[w], PA, PC); PA = sA[w] * PA; }
    }
    float EA = Ae * PA;
    float EC = fmaf(Ce, PA, PC);
    float Rt_ = __fdividef(EA * C_R0, fmaf(EC, C_R0, 1.0f));   // R entering segment

    // ---- phase 3: closed-form outputs; den telescopes: den_j = L_j * rl_{j-1} ----
    float nn[STEPS];
    float ns = 0.0f;
    float rlPrev = 1.0f;
#pragma unroll
    for (int j = 0; j < STEPS; ++j) {
        float L   = fmaf(Cj[j], Rt_, 1.0f);
        float rlj = __fdividef(1.0f, L);
        lsR[SIDX(seg + j)] = (Aj[j] * Rt_) * rlj;
        float den = L * rlPrev;
        ns += kk[j] * __logf(den);
        nn[j] = ns;
        rlPrev = rlj;
    }

    // ---- phase 4: two-level prefix sum of per-lane N totals ----
    float S = ns;
#pragma unroll
    for (int o = 1; o < 64; o <<= 1) {
        float Sp = __shfl_up(S, (unsigned)o, 64);
        if (lane >= o) S += Sp;
    }
    if (lane == 63) sS[wid] = S;
    __syncthreads();
    float PS = C_N0;
#pragma unroll
    for (int w = 0; w < WAVES - 1; ++w) {
        if (w < wid) PS += sS[w];
    }
    float base = PS + (S - ns);
#pragma unroll
    for (int j = 0; j < STEPS; ++j)
        lsN[SIDX(seg + j)] = base + nn[j];

    __syncthreads();

    // ---- aligned store stage ----
    const size_t g0 = (size_t)b * (T + 1) + 1;         // dword index of step 0
    const int s  = (int)((16 - (g0 & 15)) & 15);       // shift to 64B boundary
    const int tl = (T - s) & 3;                        // tail dwords
    const int bodyEnd = T - tl;

    if (tid == 0) { Rt[g0 - 1] = C_R0; Nt[g0 - 1] = C_N0; }  // element [0]
    if (tid < s)  { Rt[g0 + tid] = lsR[SIDX(tid)];
                    Nt[g0 + tid] = lsN[SIDX(tid)]; }         // head
    if (tid < tl) { int m = bodyEnd + tid;
                    Rt[g0 + m] = lsR[SIDX(m)];
                    Nt[g0 + m] = lsN[SIDX(m)]; }             // tail

#pragma unroll
    for (int q = 0; q < 4; ++q) {                      // body: 64B-aligned f4
        int m0 = s + q * 1024 + tid * 4;
        if (m0 + 4 <= bodyEnd) {
            f4 r, n;
#pragma unroll
            for (int c = 0; c < 4; ++c) {
                r[c] = lsR[SIDX(m0 + c)];
                n[c] = lsN[SIDX(m0 + c)];
            }
            *(f4*)(Rt + g0 + m0) = r;
            *(f4*)(Nt + g0 + m0) = n;
        }
    }
}

extern "C" void kernel_launch(void* const* d_in, const int* in_sizes, int n_in,
                              void* d_out, int out_size, void* d_ws, size_t ws_size,
                              hipStream_t stream)
{
    const float* params = (const float*)d_in[0];
    const float* p      = (const float*)d_in[1];
    const float* dpdt   = (const float*)d_in[2];
    const float* dtv    = (const float*)d_in[3];

    float* Rt = (float*)d_out;                       // B*(T+1)
    float* Nt = (float*)d_out + (size_t)B * (T + 1); // B*(T+1)

    crs_row_kernel<<<B, 256, 0, stream>>>(params, p, dpdt, dtv, Rt, Nt);
}